// Round 8
// baseline (138.975 us; speedup 1.0000x reference)
//
#include <hip/hip_runtime.h>
#include <math.h>

#define NB 8
#define NC 256
#define NL 4096
#define NK 65
#define NSL (NL / 16)   // 256 l-tiles per batch

typedef float vf4 __attribute__((ext_vector_type(4)));
typedef float vf2 __attribute__((ext_vector_type(2)));

// Per-block stat slots (sr, si, sq, pad) -- fully overwritten every launch,
// so no zeroing pass and no atomics are needed.
__device__ float4 g_part[NB * NSL];

// XOR-swizzled LDS addressing: row-major [NC][8] float4, bank-group
// swizzle q ^ (row&7). Uniform 8-lanes-per-4-bank-group for every FFT
// stage access pattern (b128 optimum), no pad needed.
__device__ __forceinline__ int lidx(int row, int q) {
    return (row << 3) + (q ^ (row & 7));
}

// ---------------------------------------------------------------------------
// Packed conv core: v_pk_fma_f32 with op_sel broadcast.
//   lo lane: sr += x * kre      hi lane: si += x * kim
// src0 = window vf2 pair, broadcast half h via op_sel[0]=op_sel_hi[0]=h
// (zero-cost broadcast -- no v_mov); src1 = (kre,kim) pair; src2 = acc.
// Bit-identical arithmetic to the scalar form.
// ---------------------------------------------------------------------------
#define PKFMA_EVEN(ACC, WP, K2)                                             \
    asm("v_pk_fma_f32 %0, %1, %2, %0 op_sel:[0,0,0] op_sel_hi:[0,1,1]"      \
        : "+v"(ACC) : "v"(WP), "v"(K2))
#define PKFMA_ODD(ACC, WP, K2)                                              \
    asm("v_pk_fma_f32 %0, %1, %2, %0 op_sel:[1,0,0] op_sel_hi:[1,1,1]"      \
        : "+v"(ACC) : "v"(WP), "v"(K2))

// ---------------------------------------------------------------------------
// Conv helpers (register sliding window held as ALIGNED vf2 pairs, direct
// global loads; x rows are XCD-L2/L3 resident via b = bid&7 swizzle).
// ---------------------------------------------------------------------------
#define LOAD16P(W2, off)                                                    \
    {                                                                       \
        const int g0_ = l0 + (off);                                         \
        if (g0_ >= 0 && g0_ + 16 <= NL) {  /* block-uniform branch */       \
            _Pragma("unroll")                                               \
            for (int q = 0; q < 4; ++q) {                                   \
                const float4 v_ = *(const float4*)(xr + g0_ + 4 * q);       \
                vf2 a_; a_.x = v_.x; a_.y = v_.y; W2[2*q]   = a_;           \
                vf2 b_; b_.x = v_.z; b_.y = v_.w; W2[2*q+1] = b_;           \
            }                                                               \
        } else {                                                            \
            _Pragma("unroll")                                               \
            for (int q = 0; q < 8; ++q) {                                   \
                const int g_ = g0_ + 2 * q;                                 \
                vf2 a_;                                                     \
                a_.x = (g_     >= 0 && g_     < NL) ? xr[g_]     : 0.0f;    \
                a_.y = (g_ + 1 >= 0 && g_ + 1 < NL) ? xr[g_ + 1] : 0.0f;    \
                W2[q] = a_;                                                 \
            }                                                               \
        }                                                                   \
    }

// taps tb..tb+15 over window LoP[0..7] ++ HiP[0..7] (16 pairs = 32 floats)
#define CHUNK16PK(LoP, HiP, tb)                                             \
    {                                                                       \
        _Pragma("unroll")                                                   \
        for (int j2 = 0; j2 < 16; ++j2) {                                   \
            vf2 k2_; k2_.x = kre[(tb) + j2]; k2_.y = kim[(tb) + j2];        \
            _Pragma("unroll")                                               \
            for (int i = 0; i < 16; ++i) {                                  \
                const int w_ = i + j2;                                      \
                const int p_ = w_ >> 1;                                     \
                vf2 wp_ = (p_ < 8) ? LoP[p_] : HiP[p_ - 8];                 \
                if ((w_ & 1) == 0) { PKFMA_EVEN(s2[i], wp_, k2_); }         \
                else               { PKFMA_ODD (s2[i], wp_, k2_); }         \
            }                                                               \
        }                                                                   \
    }

__device__ __forceinline__ int digitrev_shift(int pp) {
    int k = ((pp & 3) << 6) | (((pp >> 2) & 3) << 4)
          | (((pp >> 4) & 3) << 2) | ((pp >> 6) & 3);
    return k ^ 128;  // fftshift
}

// ---------------------------------------------------------------------------
// Fused: conv (65 taps, 4-buffer prefetch register window, TRUE packed-f32
// FMA via inline asm) + pre-weight stats + weight (inv_std deferred by
// linearity) + 256-pt radix-4 FFT over channels (stages 0-2 in LDS; stage 3
// fused into the digit-reversed NONTEMPORAL store) + per-block stat slot.
// LDS padded to 36 KB + launch_bounds(256,4): proven regime (R3/R6: 5/CU
// caps VGPR -> scratch spill, WRITE_SIZE is the tripwire; R4: nt stores
// keep out of L2 so x owns the XCD L2/L3 path).
// ---------------------------------------------------------------------------
__global__ __launch_bounds__(256, 4) void fused_conv_fft_kernel(
    const float* __restrict__ x,
    const float* __restrict__ kre,
    const float* __restrict__ kim,
    const float* __restrict__ wmag,
    const float* __restrict__ wang,
    float* __restrict__ out,
    int out_size)
{
    // 36 KB allocated (indexing stays < NC*8): forces <=4 blocks/CU.
    __shared__ __align__(16) float4 lbuf4[NC * 9];

    const int t = threadIdx.x;              // channel
    const int b = blockIdx.x & 7;           // batch == XCD
    const int st = blockIdx.x >> 3;         // tile index within batch
    const int l0 = st << 4;                 // tile base
    const int lane = t & 63, wv = t >> 6;

    const float* xr = x + (size_t)b * NC * NL + (size_t)t * NL;  // own row
    const bool interleaved = (out_size >= 2 * NB * NC * NL);

    vf2 s2[16];                             // packed (sr, si) accumulators
    #pragma unroll
    for (int i = 0; i < 16; ++i) { s2[i].x = 0.0f; s2[i].y = 0.0f; }

    // ---- conv: 65 taps, 4-buffer prefetched sliding window, no barriers --
    vf2 W0[8], W1[8], W2[8], W3[8];
    LOAD16P(W0, -32);
    LOAD16P(W1, -16);
    LOAD16P(W2, 0);
    LOAD16P(W3, 16);
    CHUNK16PK(W0, W1, 0);    // taps  0..15
    LOAD16P(W0, 32);         // words [32,48) -> consumed by chunk 48 + tail
    CHUNK16PK(W1, W2, 16);   // taps 16..31
    CHUNK16PK(W2, W3, 32);   // taps 32..47
    CHUNK16PK(W3, W0, 48);   // taps 48..63
    {   // tail tap j = 64: words rel [32, 47] == W0 pairs 0..7
        vf2 k2_; k2_.x = kre[64]; k2_.y = kim[64];
        #pragma unroll
        for (int i = 0; i < 16; ++i) {
            vf2 wp_ = W0[i >> 1];
            if ((i & 1) == 0) { PKFMA_EVEN(s2[i], wp_, k2_); }
            else              { PKFMA_ODD (s2[i], wp_, k2_); }
        }
    }

    // ---- stats on y = (sr, -si), PRE-weight (un-normalized), packed ----
    vf2 tsum; tsum.x = 0.0f; tsum.y = 0.0f;
    vf2 tsq2; tsq2.x = 0.0f; tsq2.y = 0.0f;
    #pragma unroll
    for (int i = 0; i < 16; ++i) {
        tsum = tsum + s2[i];
        tsq2 = __builtin_elementwise_fma(s2[i], s2[i], tsq2);
    }
    float tsr = tsum.x, tsi = -tsum.y, tsq = tsq2.x + tsq2.y;

    // ---- weight & twiddle constants (after conv: low conv-phase liveness) --
    float sw, cw;
    sincosf(wang[t], &sw, &cw);
    const float wm = wmag[t];
    const float wgr =  wm * cw;             // weight WITHOUT inv_std
    const float wgi = -wm * sw;
    float tw64r, tw64i;                     // exp(-2*pi*i*lane/256)
    {
        float ang = (float)lane * 0.024543692606170260f;  // 2*pi/256
        float s, c;
        sincosf(ang, &s, &c);
        tw64r = c; tw64i = -s;
    }

    // ---- weight: y' = y * (wgr + i*wgi) -> own FFT row (first LDS use) ----
    #pragma unroll
    for (int k = 0; k < 8; ++k) {
        float srA = s2[2*k].x,   siA = s2[2*k].y;
        float srB = s2[2*k+1].x, siB = s2[2*k+1].y;
        float4 o;
        o.x = srA * wgr + siA * wgi;
        o.y = srA * wgi - siA * wgr;
        o.z = srB * wgr + siB * wgi;
        o.w = srB * wgi - siB * wgr;
        lbuf4[lidx(t, k)] = o;
    }
    __syncthreads();

    // ---- FFT stages 0..2 over channels (LDS) ----
    // Twiddles: stage exponents e<64 -> w1 from per-thread tw64 via __shfl;
    // w2 = w1^2, w3 = w1*w2 (double-angle, exact).
    #pragma unroll
    for (int s = 0; s < 3; ++s) {
        const int shift = 2 * s;
        const int q = 64 >> shift;
        #pragma unroll
        for (int it = 0; it < 2; ++it) {
            int task = it * 256 + t;       // 512 tasks = 64 butterflies x 8 lpairs
            int lpp = task & 7;
            int m = task >> 3;
            int j = m & (q - 1);
            int blk = m >> (6 - shift);
            int base2 = blk << (8 - shift);

            int ca = base2 + j;
            float4 a0 = lbuf4[lidx(ca, lpp)];
            float4 a1 = lbuf4[lidx(ca + q, lpp)];
            float4 a2 = lbuf4[lidx(ca + 2*q, lpp)];
            float4 a3 = lbuf4[lidx(ca + 3*q, lpp)];

            int e = j << shift;            // e < 64 for stages 0..2
            float w1r = __shfl(tw64r, e);
            float w1i = __shfl(tw64i, e);
            float w2r = fmaf(w1r, w1r, -(w1i * w1i));
            float w2i = 2.0f * w1r * w1i;
            float w3r = w2r * w1r - w2i * w1i;
            float w3i = w2r * w1i + w2i * w1r;

            float4 b0, b1, b2, b3;
            {
                float t0r = a0.x + a2.x, t0i = a0.y + a2.y;
                float t1r = a0.x - a2.x, t1i = a0.y - a2.y;
                float t2r = a1.x + a3.x, t2i = a1.y + a3.y;
                float t3r = a1.x - a3.x, t3i = a1.y - a3.y;
                b0.x = t0r + t2r;       b0.y = t0i + t2i;
                float b2r = t0r - t2r,  b2i = t0i - t2i;
                float b1r = t1r + t3i,  b1i = t1i - t3r;
                float b3r = t1r - t3i,  b3i = t1i + t3r;
                b1.x = b1r*w1r - b1i*w1i;  b1.y = b1r*w1i + b1i*w1r;
                b2.x = b2r*w2r - b2i*w2i;  b2.y = b2r*w2i + b2i*w2r;
                b3.x = b3r*w3r - b3i*w3i;  b3.y = b3r*w3i + b3i*w3r;
            }
            {
                float t0r = a0.z + a2.z, t0i = a0.w + a2.w;
                float t1r = a0.z - a2.z, t1i = a0.w - a2.w;
                float t2r = a1.z + a3.z, t2i = a1.w + a3.w;
                float t3r = a1.z - a3.z, t3i = a1.w - a3.w;
                b0.z = t0r + t2r;       b0.w = t0i + t2i;
                float b2r = t0r - t2r,  b2i = t0i - t2i;
                float b1r = t1r + t3i,  b1i = t1i - t3r;
                float b3r = t1r - t3i,  b3i = t1i + t3r;
                b1.z = b1r*w1r - b1i*w1i;  b1.w = b1r*w1i + b1i*w1r;
                b2.z = b2r*w2r - b2i*w2i;  b2.w = b2r*w2i + b2i*w2r;
                b3.z = b3r*w3r - b3i*w3i;  b3.w = b3r*w3i + b3i*w3r;
            }
            lbuf4[lidx(ca, lpp)]         = b0;
            lbuf4[lidx(ca + q, lpp)]     = b1;
            lbuf4[lidx(ca + 2*q, lpp)]   = b2;
            lbuf4[lidx(ca + 3*q, lpp)]   = b3;
        }
        __syncthreads();
    }

    // ---- FFT stage 3 (q=1, w=1) fused with digit-reverse + fftshift +
    //      NONTEMPORAL store: butterfly outputs ARE final rows ca..ca+3 ----
    #pragma unroll
    for (int it = 0; it < 2; ++it) {
        int task = it * 256 + t;
        int lpp = task & 7;
        int m = task >> 3;                 // 0..63
        int ca = m << 2;
        float4 a0 = lbuf4[lidx(ca + 0, lpp)];
        float4 a1 = lbuf4[lidx(ca + 1, lpp)];
        float4 a2 = lbuf4[lidx(ca + 2, lpp)];
        float4 a3 = lbuf4[lidx(ca + 3, lpp)];

        float4 b0, b1, b2, b3;
        {
            float t0r = a0.x + a2.x, t0i = a0.y + a2.y;
            float t1r = a0.x - a2.x, t1i = a0.y - a2.y;
            float t2r = a1.x + a3.x, t2i = a1.y + a3.y;
            float t3r = a1.x - a3.x, t3i = a1.y - a3.y;
            b0.x = t0r + t2r;  b0.y = t0i + t2i;
            b2.x = t0r - t2r;  b2.y = t0i - t2i;
            b1.x = t1r + t3i;  b1.y = t1i - t3r;
            b3.x = t1r - t3i;  b3.y = t1i + t3r;
        }
        {
            float t0r = a0.z + a2.z, t0i = a0.w + a2.w;
            float t1r = a0.z - a2.z, t1i = a0.w - a2.w;
            float t2r = a1.z + a3.z, t2i = a1.w + a3.w;
            float t3r = a1.z - a3.z, t3i = a1.w - a3.w;
            b0.z = t0r + t2r;  b0.w = t0i + t2i;
            b2.z = t0r - t2r;  b2.w = t0i - t2i;
            b1.z = t1r + t3i;  b1.w = t1i - t3r;
            b3.z = t1r - t3i;  b3.w = t1i + t3r;
        }

        float4 bb[4] = { b0, b1, b2, b3 };
        #pragma unroll
        for (int mm = 0; mm < 4; ++mm) {
            int cout = digitrev_shift(ca + mm);
            float4 v = bb[mm];
            if (interleaved) {
                size_t fi = 2 * ((size_t)(b * NC + cout) * NL + l0) + 4 * lpp;
                if (fi + 4 <= (size_t)out_size) {
                    vf4 o4; o4.x = v.x; o4.y = v.y; o4.z = v.z; o4.w = v.w;
                    __builtin_nontemporal_store(o4, (vf4*)(out + fi));
                }
            } else {
                size_t fi = (size_t)(b * NC + cout) * NL + l0 + 2 * lpp;
                if (fi + 2 <= (size_t)out_size) {
                    vf2 o2; o2.x = v.x; o2.y = v.z;
                    __builtin_nontemporal_store(o2, (vf2*)(out + fi));
                }
            }
        }
    }

    // ---- block stats -> dedicated slot (reduce via LDS alias) ----
    #pragma unroll
    for (int off = 32; off > 0; off >>= 1) {
        tsr += __shfl_down(tsr, off);
        tsi += __shfl_down(tsi, off);
        tsq += __shfl_down(tsq, off);
    }
    __syncthreads();                        // stage-3 LDS reads complete
    float* redf = (float*)lbuf4;
    if (lane == 0) { redf[wv*3+0] = tsr; redf[wv*3+1] = tsi; redf[wv*3+2] = tsq; }
    __syncthreads();
    if (t == 0) {
        float a0 = 0.0f, a1 = 0.0f, a2 = 0.0f;
        #pragma unroll
        for (int i = 0; i < 4; ++i) { a0 += redf[i*3]; a1 += redf[i*3+1]; a2 += redf[i*3+2]; }
        g_part[b * NSL + st] = make_float4(a0, a1, a2, 0.0f);
    }
}

// ---------------------------------------------------------------------------
// Per-batch inv_std from g_part (each block redundantly reduces its own
// batch's 256 slots -- 4 KB, L2-hot) + contiguous nontemporal scale of its
// out range. XCD-affine: block j -> batch j&7 (same swizzle as fused).
// ---------------------------------------------------------------------------
__global__ __launch_bounds__(256) void scale_out_kernel(
    float* __restrict__ out, int out_size)
{
    __shared__ float sred[13];
    const int t = threadIdx.x;
    const int j = blockIdx.x;               // 0..2047
    const int b = j & 7;                    // batch == XCD
    const int seg = j >> 3;                 // 256 segments per batch
    const int lane = t & 63, wv = t >> 6;

    // reduce batch b's 256 slots (thread t -> slot t)
    float4 p = g_part[b * NSL + t];
    float psr = p.x, psi = p.y, psq = p.z;
    #pragma unroll
    for (int off = 32; off > 0; off >>= 1) {
        psr += __shfl_down(psr, off);
        psi += __shfl_down(psi, off);
        psq += __shfl_down(psq, off);
    }
    if (lane == 0) { sred[wv*3+0] = psr; sred[wv*3+1] = psi; sred[wv*3+2] = psq; }
    __syncthreads();
    if (t == 0) {
        float a0 = 0.0f, a1 = 0.0f, a2 = 0.0f;
        #pragma unroll
        for (int i = 0; i < 4; ++i) { a0 += sred[i*3]; a1 += sred[i*3+1]; a2 += sred[i*3+2]; }
        const float n = (float)(NC * NL);
        float var = (a2 - (a0*a0 + a1*a1)/n) / (n - 1.0f);
        sred[12] = rsqrtf(var);
    }
    __syncthreads();
    const float inv = sred[12];

    const int fpbatch = out_size >> 3;      // floats per batch
    const int fpseg = fpbatch >> 8;         // floats per segment
    const int base = b * fpbatch + seg * fpseg;
    if ((fpseg & 3) == 0 && ((size_t)(out + base) & 15) == 0) {
        const int n4 = fpseg >> 2;
        for (int i = t; i < n4; i += 256) {
            vf4* p4 = (vf4*)(out + base) + i;
            vf4 v = __builtin_nontemporal_load(p4);
            v.x *= inv; v.y *= inv; v.z *= inv; v.w *= inv;
            __builtin_nontemporal_store(v, p4);
        }
    } else {
        for (int i = t; i < fpseg; i += 256) out[base + i] *= inv;
    }
    // tail (out_size not divisible by 2048): belongs to the last batch,
    // and block j==2047 has b==7.
    if (j == 2047) {
        for (int i = ((out_size >> 11) << 11) + t; i < out_size; i += 256)
            out[i] *= inv;
    }
}

extern "C" void kernel_launch(void* const* d_in, const int* in_sizes, int n_in,
                              void* d_out, int out_size, void* d_ws, size_t ws_size,
                              hipStream_t stream)
{
    const float* x   = (const float*)d_in[0];
    const float* kre = (const float*)d_in[1];
    const float* kim = (const float*)d_in[2];
    const float* wm  = (const float*)d_in[3];
    const float* wa  = (const float*)d_in[4];
    float* out = (float*)d_out;
    (void)d_ws; (void)ws_size;

    fused_conv_fft_kernel<<<NB * NSL, 256, 0, stream>>>(x, kre, kim, wm, wa,
                                                        out, out_size);
    scale_out_kernel<<<2048, 256, 0, stream>>>(out, out_size);
}

// Round 9
// 134.322 us; speedup vs baseline: 1.0346x; 1.0346x over previous
//
#include <hip/hip_runtime.h>
#include <math.h>

#define NB 8
#define NC 256
#define NL 4096
#define NK 65
#define NSL (NL / 16)   // 256 l-tiles per batch

typedef float vf4 __attribute__((ext_vector_type(4)));
typedef float vf2 __attribute__((ext_vector_type(2)));

// Per-block stat slots (sr, si, sq, pad) -- fully overwritten every launch,
// so no zeroing pass and no atomics are needed.
__device__ float4 g_part[NB * NSL];

// XOR-swizzled LDS addressing: row-major [NC][8] float4, bank-group
// swizzle q ^ (row&7). Uniform 8-lanes-per-4-bank-group for every FFT
// stage access pattern (b128 optimum), no pad needed.
__device__ __forceinline__ int lidx(int row, int q) {
    return (row << 3) + (q ^ (row & 7));
}

// ---------------------------------------------------------------------------
// Packed conv core: v_pk_fma_f32 with op_sel broadcast.
//   lo lane: sr += x * kre      hi lane: si += x * kim
// src0 = window vf2 pair, broadcast half h via op_sel[0]=op_sel_hi[0]=h
// (zero-cost broadcast -- no v_mov); src1 = (kre,kim) pair; src2 = acc.
// Bit-identical arithmetic to the scalar form.
// ---------------------------------------------------------------------------
#define PKFMA_EVEN(ACC, WP, K2)                                             \
    asm("v_pk_fma_f32 %0, %1, %2, %0 op_sel:[0,0,0] op_sel_hi:[0,1,1]"      \
        : "+v"(ACC) : "v"(WP), "v"(K2))
#define PKFMA_ODD(ACC, WP, K2)                                              \
    asm("v_pk_fma_f32 %0, %1, %2, %0 op_sel:[1,0,0] op_sel_hi:[1,1,1]"      \
        : "+v"(ACC) : "v"(WP), "v"(K2))

// ---------------------------------------------------------------------------
// Conv helpers (register sliding window held as ALIGNED vf2 pairs, direct
// global loads; x rows are XCD-L2/L3 resident via b = bid&7 swizzle).
// ---------------------------------------------------------------------------
#define LOAD16P(W2, off)                                                    \
    {                                                                       \
        const int g0_ = l0 + (off);                                         \
        if (g0_ >= 0 && g0_ + 16 <= NL) {  /* block-uniform branch */       \
            _Pragma("unroll")                                               \
            for (int q = 0; q < 4; ++q) {                                   \
                const float4 v_ = *(const float4*)(xr + g0_ + 4 * q);       \
                vf2 a_; a_.x = v_.x; a_.y = v_.y; W2[2*q]   = a_;           \
                vf2 b_; b_.x = v_.z; b_.y = v_.w; W2[2*q+1] = b_;           \
            }                                                               \
        } else {                                                            \
            _Pragma("unroll")                                               \
            for (int q = 0; q < 8; ++q) {                                   \
                const int g_ = g0_ + 2 * q;                                 \
                vf2 a_;                                                     \
                a_.x = (g_     >= 0 && g_     < NL) ? xr[g_]     : 0.0f;    \
                a_.y = (g_ + 1 >= 0 && g_ + 1 < NL) ? xr[g_ + 1] : 0.0f;    \
                W2[q] = a_;                                                 \
            }                                                               \
        }                                                                   \
    }

// taps tb..tb+15 over window LoP[0..7] ++ HiP[0..7] (16 pairs = 32 floats)
#define CHUNK16PK(LoP, HiP, tb)                                             \
    {                                                                       \
        _Pragma("unroll")                                                   \
        for (int j2 = 0; j2 < 16; ++j2) {                                   \
            vf2 k2_; k2_.x = kre[(tb) + j2]; k2_.y = kim[(tb) + j2];        \
            _Pragma("unroll")                                               \
            for (int i = 0; i < 16; ++i) {                                  \
                const int w_ = i + j2;                                      \
                const int p_ = w_ >> 1;                                     \
                vf2 wp_ = (p_ < 8) ? LoP[p_] : HiP[p_ - 8];                 \
                if ((w_ & 1) == 0) { PKFMA_EVEN(s2[i], wp_, k2_); }         \
                else               { PKFMA_ODD (s2[i], wp_, k2_); }         \
            }                                                               \
        }                                                                   \
    }

__device__ __forceinline__ int digitrev_shift(int pp) {
    int k = ((pp & 3) << 6) | (((pp >> 2) & 3) << 4)
          | (((pp >> 4) & 3) << 2) | ((pp >> 6) & 3);
    return k ^ 128;  // fftshift
}

// ---------------------------------------------------------------------------
// Fused: conv (65 taps, 4-buffer prefetch register window, packed-f32 FMA
// via inline asm) + pre-weight stats + weight (inv_std deferred by
// linearity) + 256-pt radix-4 FFT over channels (stages 0-2 in LDS; stage 3
// fused into the digit-reversed store) + per-block stat slot.
// R9: stores go THROUGH L2 (no nt). At 4/CU there is no write amplification
// (R1: WRITE == out size exactly), and out stays L2/L3-resident so the
// scale pass reads cache-hot instead of round-tripping HBM (R3's remainder
// 51 us vs nt rounds' 85-90 us). LDS padded to 36 KB + launch_bounds(256,4):
// proven regime (R3/R6: 5/CU caps VGPR -> scratch spill).
// ---------------------------------------------------------------------------
__global__ __launch_bounds__(256, 4) void fused_conv_fft_kernel(
    const float* __restrict__ x,
    const float* __restrict__ kre,
    const float* __restrict__ kim,
    const float* __restrict__ wmag,
    const float* __restrict__ wang,
    float* __restrict__ out,
    int out_size)
{
    // 36 KB allocated (indexing stays < NC*8): forces <=4 blocks/CU.
    __shared__ __align__(16) float4 lbuf4[NC * 9];

    const int t = threadIdx.x;              // channel
    const int b = blockIdx.x & 7;           // batch == XCD
    const int st = blockIdx.x >> 3;         // tile index within batch
    const int l0 = st << 4;                 // tile base
    const int lane = t & 63, wv = t >> 6;

    const float* xr = x + (size_t)b * NC * NL + (size_t)t * NL;  // own row
    const bool interleaved = (out_size >= 2 * NB * NC * NL);

    vf2 s2[16];                             // packed (sr, si) accumulators
    #pragma unroll
    for (int i = 0; i < 16; ++i) { s2[i].x = 0.0f; s2[i].y = 0.0f; }

    // ---- conv: 65 taps, 4-buffer prefetched sliding window, no barriers --
    vf2 W0[8], W1[8], W2[8], W3[8];
    LOAD16P(W0, -32);
    LOAD16P(W1, -16);
    LOAD16P(W2, 0);
    LOAD16P(W3, 16);
    CHUNK16PK(W0, W1, 0);    // taps  0..15
    LOAD16P(W0, 32);         // words [32,48) -> consumed by chunk 48 + tail
    CHUNK16PK(W1, W2, 16);   // taps 16..31
    CHUNK16PK(W2, W3, 32);   // taps 32..47
    CHUNK16PK(W3, W0, 48);   // taps 48..63
    {   // tail tap j = 64: words rel [32, 47] == W0 pairs 0..7
        vf2 k2_; k2_.x = kre[64]; k2_.y = kim[64];
        #pragma unroll
        for (int i = 0; i < 16; ++i) {
            vf2 wp_ = W0[i >> 1];
            if ((i & 1) == 0) { PKFMA_EVEN(s2[i], wp_, k2_); }
            else              { PKFMA_ODD (s2[i], wp_, k2_); }
        }
    }

    // ---- stats on y = (sr, -si), PRE-weight (un-normalized), packed ----
    vf2 tsum; tsum.x = 0.0f; tsum.y = 0.0f;
    vf2 tsq2; tsq2.x = 0.0f; tsq2.y = 0.0f;
    #pragma unroll
    for (int i = 0; i < 16; ++i) {
        tsum = tsum + s2[i];
        tsq2 = __builtin_elementwise_fma(s2[i], s2[i], tsq2);
    }
    float tsr = tsum.x, tsi = -tsum.y, tsq = tsq2.x + tsq2.y;

    // ---- weight & twiddle constants (after conv: low conv-phase liveness) --
    float sw, cw;
    sincosf(wang[t], &sw, &cw);
    const float wm = wmag[t];
    const float wgr =  wm * cw;             // weight WITHOUT inv_std
    const float wgi = -wm * sw;
    float tw64r, tw64i;                     // exp(-2*pi*i*lane/256)
    {
        float ang = (float)lane * 0.024543692606170260f;  // 2*pi/256
        float s, c;
        sincosf(ang, &s, &c);
        tw64r = c; tw64i = -s;
    }

    // ---- weight: y' = y * (wgr + i*wgi) -> own FFT row (first LDS use) ----
    #pragma unroll
    for (int k = 0; k < 8; ++k) {
        float srA = s2[2*k].x,   siA = s2[2*k].y;
        float srB = s2[2*k+1].x, siB = s2[2*k+1].y;
        float4 o;
        o.x = srA * wgr + siA * wgi;
        o.y = srA * wgi - siA * wgr;
        o.z = srB * wgr + siB * wgi;
        o.w = srB * wgi - siB * wgr;
        lbuf4[lidx(t, k)] = o;
    }
    __syncthreads();

    // ---- FFT stages 0..2 over channels (LDS) ----
    // Twiddles: stage exponents e<64 -> w1 from per-thread tw64 via __shfl;
    // w2 = w1^2, w3 = w1*w2 (double-angle, exact).
    #pragma unroll
    for (int s = 0; s < 3; ++s) {
        const int shift = 2 * s;
        const int q = 64 >> shift;
        #pragma unroll
        for (int it = 0; it < 2; ++it) {
            int task = it * 256 + t;       // 512 tasks = 64 butterflies x 8 lpairs
            int lpp = task & 7;
            int m = task >> 3;
            int j = m & (q - 1);
            int blk = m >> (6 - shift);
            int base2 = blk << (8 - shift);

            int ca = base2 + j;
            float4 a0 = lbuf4[lidx(ca, lpp)];
            float4 a1 = lbuf4[lidx(ca + q, lpp)];
            float4 a2 = lbuf4[lidx(ca + 2*q, lpp)];
            float4 a3 = lbuf4[lidx(ca + 3*q, lpp)];

            int e = j << shift;            // e < 64 for stages 0..2
            float w1r = __shfl(tw64r, e);
            float w1i = __shfl(tw64i, e);
            float w2r = fmaf(w1r, w1r, -(w1i * w1i));
            float w2i = 2.0f * w1r * w1i;
            float w3r = w2r * w1r - w2i * w1i;
            float w3i = w2r * w1i + w2i * w1r;

            float4 b0, b1, b2, b3;
            {
                float t0r = a0.x + a2.x, t0i = a0.y + a2.y;
                float t1r = a0.x - a2.x, t1i = a0.y - a2.y;
                float t2r = a1.x + a3.x, t2i = a1.y + a3.y;
                float t3r = a1.x - a3.x, t3i = a1.y - a3.y;
                b0.x = t0r + t2r;       b0.y = t0i + t2i;
                float b2r = t0r - t2r,  b2i = t0i - t2i;
                float b1r = t1r + t3i,  b1i = t1i - t3r;
                float b3r = t1r - t3i,  b3i = t1i + t3r;
                b1.x = b1r*w1r - b1i*w1i;  b1.y = b1r*w1i + b1i*w1r;
                b2.x = b2r*w2r - b2i*w2i;  b2.y = b2r*w2i + b2i*w2r;
                b3.x = b3r*w3r - b3i*w3i;  b3.y = b3r*w3i + b3i*w3r;
            }
            {
                float t0r = a0.z + a2.z, t0i = a0.w + a2.w;
                float t1r = a0.z - a2.z, t1i = a0.w - a2.w;
                float t2r = a1.z + a3.z, t2i = a1.w + a3.w;
                float t3r = a1.z - a3.z, t3i = a1.w - a3.w;
                b0.z = t0r + t2r;       b0.w = t0i + t2i;
                float b2r = t0r - t2r,  b2i = t0i - t2i;
                float b1r = t1r + t3i,  b1i = t1i - t3r;
                float b3r = t1r - t3i,  b3i = t1i + t3r;
                b1.z = b1r*w1r - b1i*w1i;  b1.w = b1r*w1i + b1i*w1r;
                b2.z = b2r*w2r - b2i*w2i;  b2.w = b2r*w2i + b2i*w2r;
                b3.z = b3r*w3r - b3i*w3i;  b3.w = b3r*w3i + b3i*w3r;
            }
            lbuf4[lidx(ca, lpp)]         = b0;
            lbuf4[lidx(ca + q, lpp)]     = b1;
            lbuf4[lidx(ca + 2*q, lpp)]   = b2;
            lbuf4[lidx(ca + 3*q, lpp)]   = b3;
        }
        __syncthreads();
    }

    // ---- FFT stage 3 (q=1, w=1) fused with digit-reverse + fftshift +
    //      store THROUGH L2: butterfly outputs ARE final rows ca..ca+3 ----
    #pragma unroll
    for (int it = 0; it < 2; ++it) {
        int task = it * 256 + t;
        int lpp = task & 7;
        int m = task >> 3;                 // 0..63
        int ca = m << 2;
        float4 a0 = lbuf4[lidx(ca + 0, lpp)];
        float4 a1 = lbuf4[lidx(ca + 1, lpp)];
        float4 a2 = lbuf4[lidx(ca + 2, lpp)];
        float4 a3 = lbuf4[lidx(ca + 3, lpp)];

        float4 b0, b1, b2, b3;
        {
            float t0r = a0.x + a2.x, t0i = a0.y + a2.y;
            float t1r = a0.x - a2.x, t1i = a0.y - a2.y;
            float t2r = a1.x + a3.x, t2i = a1.y + a3.y;
            float t3r = a1.x - a3.x, t3i = a1.y - a3.y;
            b0.x = t0r + t2r;  b0.y = t0i + t2i;
            b2.x = t0r - t2r;  b2.y = t0i - t2i;
            b1.x = t1r + t3i;  b1.y = t1i - t3r;
            b3.x = t1r - t3i;  b3.y = t1i + t3r;
        }
        {
            float t0r = a0.z + a2.z, t0i = a0.w + a2.w;
            float t1r = a0.z - a2.z, t1i = a0.w - a2.w;
            float t2r = a1.z + a3.z, t2i = a1.w + a3.w;
            float t3r = a1.z - a3.z, t3i = a1.w - a3.w;
            b0.z = t0r + t2r;  b0.w = t0i + t2i;
            b2.z = t0r - t2r;  b2.w = t0i - t2i;
            b1.z = t1r + t3i;  b1.w = t1i - t3r;
            b3.z = t1r - t3i;  b3.w = t1i + t3r;
        }

        float4 bb[4] = { b0, b1, b2, b3 };
        #pragma unroll
        for (int mm = 0; mm < 4; ++mm) {
            int cout = digitrev_shift(ca + mm);
            float4 v = bb[mm];
            if (interleaved) {
                size_t fi = 2 * ((size_t)(b * NC + cout) * NL + l0) + 4 * lpp;
                if (fi + 4 <= (size_t)out_size) {
                    *(float4*)(out + fi) = v;
                }
            } else {
                size_t fi = (size_t)(b * NC + cout) * NL + l0 + 2 * lpp;
                if (fi + 2 <= (size_t)out_size) {
                    float2 o2; o2.x = v.x; o2.y = v.z;
                    *(float2*)(out + fi) = o2;
                }
            }
        }
    }

    // ---- block stats -> dedicated slot (reduce via LDS alias) ----
    #pragma unroll
    for (int off = 32; off > 0; off >>= 1) {
        tsr += __shfl_down(tsr, off);
        tsi += __shfl_down(tsi, off);
        tsq += __shfl_down(tsq, off);
    }
    __syncthreads();                        // stage-3 LDS reads complete
    float* redf = (float*)lbuf4;
    if (lane == 0) { redf[wv*3+0] = tsr; redf[wv*3+1] = tsi; redf[wv*3+2] = tsq; }
    __syncthreads();
    if (t == 0) {
        float a0 = 0.0f, a1 = 0.0f, a2 = 0.0f;
        #pragma unroll
        for (int i = 0; i < 4; ++i) { a0 += redf[i*3]; a1 += redf[i*3+1]; a2 += redf[i*3+2]; }
        g_part[b * NSL + st] = make_float4(a0, a1, a2, 0.0f);
    }
}

// ---------------------------------------------------------------------------
// Per-batch inv_std from g_part (each block redundantly reduces its own
// batch's 256 slots -- 4 KB, L2-hot) + contiguous scale of its out range,
// all THROUGH L2/L3 (out was written through L2 by the fused kernel and is
// still cache-resident: ~4.2 MB/XCD in L2, 33.5 MB total << 256 MB L3).
// XCD-affine: block j -> batch j&7 (same swizzle as fused).
// ---------------------------------------------------------------------------
__global__ __launch_bounds__(256) void scale_out_kernel(
    float* __restrict__ out, int out_size)
{
    __shared__ float sred[13];
    const int t = threadIdx.x;
    const int j = blockIdx.x;               // 0..2047
    const int b = j & 7;                    // batch == XCD
    const int seg = j >> 3;                 // 256 segments per batch
    const int lane = t & 63, wv = t >> 6;

    // reduce batch b's 256 slots (thread t -> slot t)
    float4 p = g_part[b * NSL + t];
    float psr = p.x, psi = p.y, psq = p.z;
    #pragma unroll
    for (int off = 32; off > 0; off >>= 1) {
        psr += __shfl_down(psr, off);
        psi += __shfl_down(psi, off);
        psq += __shfl_down(psq, off);
    }
    if (lane == 0) { sred[wv*3+0] = psr; sred[wv*3+1] = psi; sred[wv*3+2] = psq; }
    __syncthreads();
    if (t == 0) {
        float a0 = 0.0f, a1 = 0.0f, a2 = 0.0f;
        #pragma unroll
        for (int i = 0; i < 4; ++i) { a0 += sred[i*3]; a1 += sred[i*3+1]; a2 += sred[i*3+2]; }
        const float n = (float)(NC * NL);
        float var = (a2 - (a0*a0 + a1*a1)/n) / (n - 1.0f);
        sred[12] = rsqrtf(var);
    }
    __syncthreads();
    const float inv = sred[12];

    const int fpbatch = out_size >> 3;      // floats per batch
    const int fpseg = fpbatch >> 8;         // floats per segment
    const int base = b * fpbatch + seg * fpseg;
    if ((fpseg & 3) == 0 && ((size_t)(out + base) & 15) == 0) {
        float4* o4 = (float4*)(out + base);
        const int n4 = fpseg >> 2;
        for (int i = t; i < n4; i += 256) {
            float4 v = o4[i];
            v.x *= inv; v.y *= inv; v.z *= inv; v.w *= inv;
            o4[i] = v;
        }
    } else {
        for (int i = t; i < fpseg; i += 256) out[base + i] *= inv;
    }
    // tail (out_size not divisible by 2048): belongs to the last batch,
    // and block j==2047 has b==7.
    if (j == 2047) {
        for (int i = ((out_size >> 11) << 11) + t; i < out_size; i += 256)
            out[i] *= inv;
    }
}

extern "C" void kernel_launch(void* const* d_in, const int* in_sizes, int n_in,
                              void* d_out, int out_size, void* d_ws, size_t ws_size,
                              hipStream_t stream)
{
    const float* x   = (const float*)d_in[0];
    const float* kre = (const float*)d_in[1];
    const float* kim = (const float*)d_in[2];
    const float* wm  = (const float*)d_in[3];
    const float* wa  = (const float*)d_in[4];
    float* out = (float*)d_out;
    (void)d_ws; (void)ws_size;

    fused_conv_fft_kernel<<<NB * NSL, 256, 0, stream>>>(x, kre, kim, wm, wa,
                                                        out, out_size);
    scale_out_kernel<<<2048, 256, 0, stream>>>(out, out_size);
}